// Round 1
// baseline (2701.256 us; speedup 1.0000x reference)
//
#include <hip/hip_runtime.h>

#define NNODES 100000
#define NEDGES 1600000
#define NCOUP  800000
#define D      32
#define DE     65
#define W1_LD  68   // padded transposed-W1 row stride (272 B, 16B-aligned)

__device__ __forceinline__ float selu_f(float x) {
    const float scale = 1.0507009873554805f;
    const float alpha = 1.6732632423543772f;
    return x > 0.0f ? scale * x : scale * alpha * (__expf(x) - 1.0f);
}

__global__ __launch_bounds__(256) void edge_msg_kernel(
    const float* __restrict__ h,
    const float* __restrict__ coup,
    const float* __restrict__ W1,
    const float* __restrict__ b1,
    const float* __restrict__ W2,
    const float* __restrict__ b2,
    const int* __restrict__ senders,
    const int* __restrict__ receivers,
    float* __restrict__ out)
{
    __shared__ float sW1t[DE * W1_LD];  // [j][k] (transposed), padded rows
    __shared__ float sW2[DE * D];       // [j][d] row-major (as given)
    __shared__ float sb1[DE];
    __shared__ float sb2[D];

    for (int i = threadIdx.x; i < DE * DE; i += 256) {
        int k = i / DE;
        int j = i - k * DE;
        sW1t[j * W1_LD + k] = W1[i];    // pad tail never read (k < 65)
    }
    for (int i = threadIdx.x; i < DE * D; i += 256) sW2[i] = W2[i];
    if (threadIdx.x < DE) sb1[threadIdx.x] = b1[threadIdx.x];
    if (threadIdx.x >= 128 && threadIdx.x < 128 + D) sb2[threadIdx.x - 128] = b2[threadIdx.x - 128];
    __syncthreads();

    const int e = blockIdx.x * 256 + threadIdx.x;   // grid covers exactly NEDGES
    const int s = senders[e];
    const int r = receivers[e];

    float edgef[DE];
    const float4* hr = reinterpret_cast<const float4*>(h + (size_t)r * D);
    const float4* hs = reinterpret_cast<const float4*>(h + (size_t)s * D);
    #pragma unroll
    for (int i = 0; i < 8; ++i) {
        float4 v = hr[i];
        edgef[4*i+0] = v.x; edgef[4*i+1] = v.y; edgef[4*i+2] = v.z; edgef[4*i+3] = v.w;
    }
    #pragma unroll
    for (int i = 0; i < 8; ++i) {
        float4 v = hs[i];
        edgef[D+4*i+0] = v.x; edgef[D+4*i+1] = v.y; edgef[D+4*i+2] = v.z; edgef[D+4*i+3] = v.w;
    }
    edgef[2*D] = coup[e < NCOUP ? e : e - NCOUP];

    float acc[D];
    #pragma unroll
    for (int d2 = 0; d2 < D; ++d2) acc[d2] = sb2[d2];

    for (int j = 0; j < DE; ++j) {
        const float* wrow = &sW1t[j * W1_LD];
        float p0 = 0.0f, p1 = 0.0f, p2 = 0.0f, p3 = 0.0f;
        #pragma unroll
        for (int k = 0; k < 64; k += 4) {
            p0 = fmaf(edgef[k+0], wrow[k+0], p0);
            p1 = fmaf(edgef[k+1], wrow[k+1], p1);
            p2 = fmaf(edgef[k+2], wrow[k+2], p2);
            p3 = fmaf(edgef[k+3], wrow[k+3], p3);
        }
        float hj = sb1[j] + fmaf(edgef[64], wrow[64], (p0 + p1) + (p2 + p3));
        hj = selu_f(hj);
        const float* w2row = &sW2[j * D];
        #pragma unroll
        for (int d2 = 0; d2 < D; ++d2) acc[d2] = fmaf(hj, w2row[d2], acc[d2]);
    }

    float* op = out + (size_t)r * D;
    #pragma unroll
    for (int d2 = 0; d2 < D; ++d2) atomicAdd(op + d2, selu_f(acc[d2]));
}

__global__ __launch_bounds__(256) void relu_kernel(float* __restrict__ out) {
    const int i = blockIdx.x * 256 + threadIdx.x;   // one float4 per thread
    float4* p = reinterpret_cast<float4*>(out);
    float4 v = p[i];
    v.x = fmaxf(v.x, 0.0f);
    v.y = fmaxf(v.y, 0.0f);
    v.z = fmaxf(v.z, 0.0f);
    v.w = fmaxf(v.w, 0.0f);
    p[i] = v;
}

extern "C" void kernel_launch(void* const* d_in, const int* in_sizes, int n_in,
                              void* d_out, int out_size, void* d_ws, size_t ws_size,
                              hipStream_t stream) {
    const float* h    = (const float*)d_in[0];
    const float* coup = (const float*)d_in[1];
    const float* W1   = (const float*)d_in[2];
    const float* b1   = (const float*)d_in[3];
    const float* W2   = (const float*)d_in[4];
    const float* b2   = (const float*)d_in[5];
    // d_in[6..9] = Wq, bq, Wk, bk: unused — softmax over a size-1 axis is 1.0
    const int* senders   = (const int*)d_in[10];
    const int* receivers = (const int*)d_in[11];
    float* out = (float*)d_out;

    hipMemsetAsync(d_out, 0, (size_t)out_size * sizeof(float), stream);
    edge_msg_kernel<<<NEDGES / 256, 256, 0, stream>>>(
        h, coup, W1, b1, W2, b2, senders, receivers, out);
    relu_kernel<<<out_size / 4 / 256, 256, 0, stream>>>(out);
}